// Round 4
// baseline (1705.761 us; speedup 1.0000x reference)
//
#include <hip/hip_runtime.h>
#include <math.h>

#define BATCH 16
#define HR 512
#define LR 128
#define N_LR (BATCH*LR*LR)   // 262144
#define N_HR (BATCH*HR*HR)   // 4194304
#define NSH 13
#define NSHIFT 169
#define TH 8                 // output rows per k_cost block
#define NW 8                 // waves per k_cost block
#define CPAD 144             // 6 left pad + 128 + 10 right pad (cols pre-clamped)
#define CROWS 40             // curr rows r0-16 .. r0+23 (clamped)

__device__ __forceinline__ int clampi(int v, int lo, int hi){ return v<lo?lo:(v>hi?hi:v); }

// 7-tap gaussian, sigma=1, normalized; t compile-time under unroll -> folds.
__device__ __forceinline__ float gk(int t){
  const float e1 = 0.60653065971263342f;
  const float e2 = 0.13533528323661270f;
  const float e3 = 0.011108996538242306f;
  const float norm = 1.0f/(1.0f + 2.0f*(e1+e2+e3));
  int a = t < 0 ? -t : t;
  float v = (a==0) ? 1.0f : (a==1 ? e1 : (a==2 ? e2 : e3));
  return v*norm;
}

// log1p(max(.,0)) + exact 4:1 downsample; dense float4 row loads (use .y/.z).
__global__ void k_downsample(const float* __restrict__ ref, const float* __restrict__ tar,
                             float* __restrict__ wref, float* __restrict__ wtar,
                             float* __restrict__ rain){
  int i = blockIdx.x*blockDim.x + threadIdx.x;
  if (i >= N_LR) return;
  int x = i & (LR-1); int y = (i >> 7) & (LR-1); int b = i >> 14;
  int base = b*HR*HR + (4*y+1)*HR + 4*x;      // 16B aligned
  float4 r1 = *(const float4*)(ref + base);
  float4 r2 = *(const float4*)(ref + base + HR);
  float4 t1 = *(const float4*)(tar + base);
  float4 t2 = *(const float4*)(tar + base + HR);
  float r00=r1.y, r01=r1.z, r10=r2.y, r11=r2.z;
  float t00=t1.y, t01=t1.z, t10=t2.y, t11=t2.z;
  wref[i] = 0.25f*(log1pf(fmaxf(r00,0.f))+log1pf(fmaxf(r01,0.f))
                 +log1pf(fmaxf(r10,0.f))+log1pf(fmaxf(r11,0.f)));
  wtar[i] = 0.25f*(log1pf(fmaxf(t00,0.f))+log1pf(fmaxf(t01,0.f))
                 +log1pf(fmaxf(t10,0.f))+log1pf(fmaxf(t11,0.f)));
  rain[i] = (0.25f*(t00+t01+t10+t11) >= 0.1f) ? 1.0f : 0.0f;
}

// Fused separable 7x7 edge-clamped gaussian; blockIdx.z selects field pair.
// Cost-decode mode (cA != nullptr): staging input is the cross-z merged argmin
// key; z=0 decodes fx = (s%13-6)*rain, z=1 decodes fy = (s/13-6)*rain —
// bit-exact vs. the old materialized fx/fy (integer-valued float * {0,1}).
__global__ void k_blur2(const float* __restrict__ in0, const float* __restrict__ in1,
                        float* __restrict__ out0, float* __restrict__ out1,
                        const float* __restrict__ m0, const float* __restrict__ m1,
                        const unsigned long long* __restrict__ cA,
                        const unsigned long long* __restrict__ cB){
  const int z = blockIdx.z;
  float* out       = z ? out1 : out0;
  const float* msk = z ? m1 : m0;
  const int r0 = blockIdx.x * 16;
  const int bb = blockIdx.y;
  const int tid = threadIdx.x;
  __shared__ float raw[22][LR];
  __shared__ float hb[22][LR];
  for (int idx = tid; idx < 22*LR; idx += 256){
    int lr = idx >> 7, c = idx & (LR-1);
    int gr = clampi(r0 - 3 + lr, 0, LR-1);
    int gi = (bb<<14) + (gr<<7) + c;
    float v;
    if (cA){
      unsigned long long kk0 = cA[gi], kk1 = cB[gi];
      unsigned long long kk = (kk1 < kk0) ? kk1 : kk0;
      int sv = (int)(kk & 0xffffffffULL);
      int dv = z ? (sv / NSH - 6) : (sv % NSH - 6);
      v = (float)dv * msk[gi];
    } else {
      const float* in = z ? in1 : in0;
      v = in[gi];
    }
    raw[lr][c] = v;
  }
  __syncthreads();
  for (int idx = tid; idx < 22*LR; idx += 256){
    int lr = idx >> 7, c = idx & (LR-1);
    float s = 0.f;
    #pragma unroll
    for (int t=-3;t<=3;++t) s += gk(t)*raw[lr][clampi(c+t,0,LR-1)];
    hb[lr][c] = s;
  }
  __syncthreads();
  for (int idx = tid; idx < 16*LR; idx += 256){
    int lr = idx >> 7, c = idx & (LR-1);
    int i = r0 + lr;
    float s = 0.f;
    #pragma unroll
    for (int t=-3;t<=3;++t) s += gk(t)*hb[clampi(i+t,0,LR-1) - (r0-3)][c];
    int gi = (bb<<14) + (i<<7) + c;
    if (msk) s *= msk[gi];
    out[gi] = s;
  }
}

// --- DPP wave64 inclusive prefix (rocPRIM scan sequence), pure VALU ---
template<int CTRL, int RM>
__device__ __forceinline__ float dpp_mov0(float x){
  return __int_as_float(__builtin_amdgcn_update_dpp(0, __float_as_int(x), CTRL, RM, 0xF, true));
}
__device__ __forceinline__ float prefix64(float x){
  x += dpp_mov0<0x111,0xF>(x);   // row_shr:1
  x += dpp_mov0<0x112,0xF>(x);   // row_shr:2
  x += dpp_mov0<0x114,0xF>(x);   // row_shr:4
  x += dpp_mov0<0x118,0xF>(x);   // row_shr:8
  x += dpp_mov0<0x142,0xA>(x);   // row_bcast:15 -> rows 1,3
  x += dpp_mov0<0x143,0xC>(x);   // row_bcast:31 -> rows 2,3
  return x;
}
__device__ __forceinline__ float bperm(int addr4, float v){
  return __int_as_float(__builtin_amdgcn_ds_bpermute(addr4, __float_as_int(v)));
}

struct TapCtx { int ia0, ib0, ia1, ib1; bool lb0ok, selA, selB; };

// Horizontal 21-tap zero-pad box via prefix-diff over the 128-col row held as
// (col=lane in v0, col=lane+64 in v1); register argmin update.
// pg1 = pf1 + T0 pre-folds the two conditional +T0 tap fixups (bit-identical:
// bperm moves bits exactly, so adding T0 before the permute on the pf1-sourced
// lanes equals the old post-permute conditional add for every lane case).
__device__ __forceinline__ void horiz_update(const TapCtx& tc, float v0, float v1, int s,
                                             unsigned long long& k0ref, unsigned long long& k1ref){
  float pf0 = prefix64(v0);
  float pf1 = prefix64(v1);
  float T0 = __int_as_float(__builtin_amdgcn_readlane(__float_as_int(pf0), 63));
  float pg1 = pf1 + T0;
  float va = tc.selA ? pf0 : pg1;      // src lane t: t>=10 ? pf0 : pg1
  float vb = tc.selB ? pf0 : pg1;      // src lane t: t>=53 ? pf0 : pg1
  float a0 = bperm(tc.ia0, va);                        // P(x+10), x=lane
  float b0 = tc.lb0ok ? bperm(tc.ib0, pf0) : 0.f;      // P(x-11) or 0
  float a1 = bperm(tc.ia1, pg1);                       // P(min(x+10,127)), x=lane+64
  float b1 = bperm(tc.ib1, vb);                        // P(x-11), x=lane+64
  float c0 = fmaxf((a0 - b0) * (1.0f/441.0f), 0.f);
  float c1 = fmaxf((a1 - b1) * (1.0f/441.0f), 0.f);
  unsigned long long k0 = ((unsigned long long)__float_as_uint(c0) << 32) | (unsigned)s;
  unsigned long long k1 = ((unsigned long long)__float_as_uint(c1) << 32) | (unsigned)s;
  if (k0 < k0ref) k0ref = k0;
  if (k1 < k1ref) k1ref = k1;
}

// Per-wave cost walk over contiguous shift range [t_lo, t_hi) in dy-major order
// (so s == t directly). q rows come straight from the column-padded LDS tile;
// vertical 21-row box built per shift, slid across the 8 output rows.
// EDGE=false (interior tiles): no row guards at all.
template<bool EDGE>
__device__ __forceinline__ void cost_loop(int r0, int lane, int t_lo, int t_hi,
    const float (*cT)[CPAD], const float* p0, const float* p1, const TapCtx& tc,
    unsigned long long* bk0, unsigned long long* bk1){
  #pragma unroll 1
  for (int t = t_lo; t < t_hi; ++t){
    const int dyi = t / NSH;
    const int dxi = t - dyi*NSH;
    const int pc = lane + dxi;                 // padded col = (x + dx) + 6, x=lane
    float v0 = 0.f, v1 = 0.f;
    #pragma unroll
    for (int wr = 0; wr <= 20; ++wr){
      if (!EDGE || ((r0 - 10 + wr) >= 0 && (r0 - 10 + wr) < LR)){
        float d0 = p0[wr] - cT[dyi + wr][pc];
        float d1 = p1[wr] - cT[dyi + wr][pc + 64];
        v0 = fmaf(d0, d0, v0);
        v1 = fmaf(d1, d1, v1);
      }
    }
    horiz_update(tc, v0, v1, t, bk0[0], bk1[0]);
    #pragma unroll
    for (int io = 1; io < TH; ++io){
      const int wrA = io + 20;                 // add leading row
      if (!EDGE || ((r0 - 10 + wrA) < LR)){
        float d0 = p0[wrA] - cT[dyi + wrA][pc];
        float d1 = p1[wrA] - cT[dyi + wrA][pc + 64];
        v0 = fmaf(d0, d0, v0);
        v1 = fmaf(d1, d1, v1);
      }
      const int wrS = io - 1;                  // subtract trailing row
      if (!EDGE || ((r0 - 10 + wrS) >= 0)){
        float d0 = p0[wrS] - cT[dyi + wrS][pc];
        float d1 = p1[wrS] - cT[dyi + wrS][pc + 64];
        v0 = fmaf(-d0, d0, v0);
        v1 = fmaf(-d1, d1, v1);
      }
      horiz_update(tc, v0, v1, t, bk0[io], bk1[io]);
    }
  }
}

// Block = (row-tile of 8, batch, shift-half). blockIdx.z splits the 169 shifts
// 85/84 -> 512 blocks = 2 blocks/CU = 4 waves/SIMD (latency hiding; LDS
// 55.8KB*2 fits 160KB, VGPR 84 << 128 cap). Each z-block writes its fully
// merged u64 argmin keys to its own buffer (plain stores, no atomics); the
// cross-z min + flow decode happens in k_blur2's staging (bit-exact).
__global__ void __launch_bounds__(512, 4)
k_cost_flow(const float* __restrict__ prev, const float* __restrict__ curr,
            unsigned long long* __restrict__ c0out, unsigned long long* __restrict__ c1out){
  const int r0 = blockIdx.x * TH;
  const int bb = blockIdx.y;
  const int z  = blockIdx.z;
  const int tid = threadIdx.x;
  const int w = tid >> 6, lane = tid & 63;
  const float* P = prev + (bb<<14);
  const float* C = curr + (bb<<14);

  __shared__ float currT[CROWS][CPAD];            // 22.5 KB
  __shared__ unsigned long long mg[4][TH*LR];     // merge slots, 32 KB

  for (int idx = tid; idx < CROWS*CPAD; idx += 512){
    int lr = idx / CPAD, j = idx - lr*CPAD;
    int gr = clampi(r0 - 16 + lr, 0, LR-1);
    int gc = clampi(j - 6, 0, LR-1);
    currT[lr][j] = C[(gr<<7) + gc];
  }

  // prev rows r0-10..r0+17 at cols (lane, lane+64), zero out of range (unused there)
  float p0[28], p1[28];
  #pragma unroll
  for (int wr = 0; wr < 28; ++wr){
    int gr = r0 - 10 + wr;
    if (gr >= 0 && gr < LR){ p0[wr] = P[(gr<<7) + lane]; p1[wr] = P[(gr<<7) + lane + 64]; }
    else                   { p0[wr] = 0.f; p1[wr] = 0.f; }
  }
  __syncthreads();

  unsigned long long bk0[TH], bk1[TH];
  #pragma unroll
  for (int io = 0; io < TH; ++io){ bk0[io] = ~0ULL; bk1[io] = ~0ULL; }

  TapCtx tc;
  tc.ia0 = ((lane + 10) & 63) << 2;
  tc.ib0 = ((lane - 11) & 63) << 2;
  tc.ia1 = (min(lane + 10, 63)) << 2;
  tc.ib1 = ((lane + 53) & 63) << 2;
  tc.lb0ok = (lane >= 11);
  tc.selA  = (lane >= 10);
  tc.selB  = (lane >= 53);

  const int base = z ? 85 : 0;                // z=0: t 0..84, z=1: t 85..168
  const int cnt  = z ? 84 : 85;
  const int t_lo = base + (cnt * w) / NW;
  const int t_hi = base + (cnt * (w+1)) / NW;

  const bool interior = (r0 >= 10) && (r0 + TH + 9 < LR);
  if (interior) cost_loop<false>(r0, lane, t_lo, t_hi, currT, p0, p1, tc, bk0, bk1);
  else          cost_loop<true >(r0, lane, t_lo, t_hi, currT, p0, p1, tc, bk0, bk1);

  // slotted tree merge: slot g=w&3, waves 0-3 write, 4-7 merge, then 4-slot min
  __syncthreads();
  const int g = w & 3;
  if (w < 4){
    #pragma unroll
    for (int io = 0; io < TH; ++io){
      mg[g][io*LR + lane]      = bk0[io];
      mg[g][io*LR + lane + 64] = bk1[io];
    }
  }
  __syncthreads();
  if (w >= 4){
    #pragma unroll
    for (int io = 0; io < TH; ++io){
      unsigned long long m0 = mg[g][io*LR + lane];
      unsigned long long m1 = mg[g][io*LR + lane + 64];
      mg[g][io*LR + lane]      = (bk0[io] < m0) ? bk0[io] : m0;
      mg[g][io*LR + lane + 64] = (bk1[io] < m1) ? bk1[io] : m1;
    }
  }
  __syncthreads();
  unsigned long long* cz = z ? c1out : c0out;
  for (int p = tid; p < TH*LR; p += 512){
    unsigned long long k  = mg[0][p];
    unsigned long long k1 = mg[1][p]; if (k1 < k) k = k1;
    unsigned long long k2 = mg[2][p]; if (k2 < k) k = k2;
    unsigned long long k3 = mg[3][p]; if (k3 < k) k = k3;
    cz[(bb<<14) + (r0<<7) + p] = k;
  }
}

// Fused: flow upsample (x4), warp of ref (border bilinear), Huber+mask, mean-reduce.
// Thread = 2 groups of 4 px; 12 shared flow loads/group (wx,wy are exact constants
// per x&3/y&3); per-px bilinear keeps round-3 operand order exactly.
__global__ void __launch_bounds__(256)
k_loss(const float* __restrict__ pred, const float* __restrict__ tar,
       const float* __restrict__ ref, const float* __restrict__ fxb,
       const float* __restrict__ fyb, float* __restrict__ out){
  const int t0 = blockIdx.x*256 + threadIdx.x;   // 0..524287
  float acc = 0.f;
  #pragma unroll
  for (int it = 0; it < 2; ++it){
    const int gq  = t0 + it*524288;
    const int b   = gq >> 16;
    const int rem = gq & 65535;
    const int y   = rem >> 7;
    const int m   = rem & 127;
    const int n = y >> 2, ky = y & 3;
    int y0; float wy;
    if (ky < 2){ y0 = max(n-1, 0); wy = (n >= 1) ? (ky == 0 ? 0.625f : 0.875f) : 0.f; }
    else       { y0 = n;           wy = (ky == 2) ? 0.125f : 0.375f; }
    const int y1 = min(y0+1, LR-1);
    const int lb = b << 14;
    const float* FxR0 = fxb + lb + (y0<<7);
    const float* FxR1 = fxb + lb + (y1<<7);
    const float* FyR0 = fyb + lb + (y0<<7);
    const float* FyR1 = fyb + lb + (y1<<7);
    const int cA = max(m-1, 0), cB = m, cC = min(m+1, LR-1);
    float xA0 = FxR0[cA], xB0 = FxR0[cB], xC0 = FxR0[cC];
    float xA1 = FxR1[cA], xB1 = FxR1[cB], xC1 = FxR1[cC];
    float yA0 = FyR0[cA], yB0 = FyR0[cB], yC0 = FyR0[cC];
    float yA1 = FyR1[cA], yB1 = FyR1[cB], yC1 = FyR1[cC];
    const bool mh = (m >= 1);
    const int hb = (b<<18) + (y<<9) + (m<<2);
    float4 pd = *(const float4*)(pred + hb);
    float4 td = *(const float4*)(tar + hb);
    const float* R = ref + (b<<18);
    const float wy1 = 1.f - wy;
    #pragma unroll
    for (int k = 0; k < 4; ++k){
      float wx;
      float lo0, hi0, lo1, hi1, flo0, fhi0, flo1, fhi1;
      if (k < 2){
        wx = mh ? (k == 0 ? 0.625f : 0.875f) : 0.f;
        lo0 = mh ? xA0 : xB0;  hi0 = mh ? xB0 : xC0;
        lo1 = mh ? xA1 : xB1;  hi1 = mh ? xB1 : xC1;
        flo0 = mh ? yA0 : yB0; fhi0 = mh ? yB0 : yC0;
        flo1 = mh ? yA1 : yB1; fhi1 = mh ? yB1 : yC1;
      } else {
        wx = (k == 2) ? 0.125f : 0.375f;
        lo0 = xB0;  hi0 = xC0;  lo1 = xB1;  hi1 = xC1;
        flo0 = yB0; fhi0 = yC0; flo1 = yB1; fhi1 = yC1;
      }
      const float w00 = wy1*(1.f-wx), w01 = wy1*wx, w10 = wy*(1.f-wx), w11 = wy*wx;
      const float fxv = 4.f*(w00*lo0 + w01*hi0 + w10*lo1 + w11*hi1);
      const float fyv = 4.f*(w00*flo0 + w01*fhi0 + w10*flo1 + w11*fhi1);
      const int x = (m<<2) + k;
      float ix = fminf(fmaxf((float)x - fxv, 0.f), (float)(HR-1));
      float iy = fminf(fmaxf((float)y - fyv, 0.f), (float)(HR-1));
      int gx0 = (int)ix; int gx1 = min(gx0+1, HR-1); float gwx = ix - (float)gx0;
      int gy0 = (int)iy; int gy1 = min(gy0+1, HR-1); float gwy = iy - (float)gy0;
      float v00 = R[(gy0<<9)+gx0], v01 = R[(gy0<<9)+gx1];
      float v10 = R[(gy1<<9)+gx0], v11 = R[(gy1<<9)+gx1];
      float tt = v00*(1.f-gwy)*(1.f-gwx) + v01*(1.f-gwy)*gwx
               + v10*gwy*(1.f-gwx)       + v11*gwy*gwx;
      float teacher = fmaxf(tt, 0.f);
      float pk = ((const float*)&pd)[k];
      float tk = ((const float*)&td)[k];
      float d  = pk - teacher;
      float ad = fabsf(d);
      float l  = ad < 0.2f ? 0.5f*d*d : 0.2f*(ad - 0.1f);
      float mm = (teacher > 0.05f || tk > 0.05f) ? 1.f : 0.f;
      acc += l*mm;
    }
  }
  acc *= (1.0f/(float)N_HR);
  #pragma unroll
  for (int o = 32; o > 0; o >>= 1) acc += __shfl_down(acc, o, 64);
  __shared__ float wsum[4];
  int lane = threadIdx.x & 63, wv = threadIdx.x >> 6;
  if (lane == 0) wsum[wv] = acc;
  __syncthreads();
  if (threadIdx.x == 0) atomicAdd(out, wsum[0]+wsum[1]+wsum[2]+wsum[3]);
}

extern "C" void kernel_launch(void* const* d_in, const int* in_sizes, int n_in,
                              void* d_out, int out_size, void* d_ws, size_t ws_size,
                              hipStream_t stream){
  const float* pred = (const float*)d_in[0];
  const float* tar  = (const float*)d_in[1];
  const float* ref  = (const float*)d_in[2];
  float* out = (float*)d_out;
  float* w = (float*)d_ws;
  float* prevW = w + 0*N_LR;
  float* currW = w + 1*N_LR;
  float* rain  = w + 2*N_LR;
  float* fxb   = w + 3*N_LR;
  float* fyb   = w + 4*N_LR;
  float* dsA   = w + 5*N_LR;   // wref_ds (dead after blur#1)
  float* dsB   = w + 6*N_LR;   // wtar_ds (dead after blur#1)
  // u64 argmin-key buffers: cA overlays dsA+dsB (2*N_LR floats = N_LR u64),
  // cB extends the workspace (peak 9*N_LR floats = 9 MB).
  unsigned long long* cKa = (unsigned long long*)(w + 5*N_LR);
  unsigned long long* cKb = (unsigned long long*)(w + 7*N_LR);

  hipMemsetAsync(d_out, 0, sizeof(float), stream);

  const int tb = 256, nb = (N_LR + tb - 1)/tb;
  k_downsample<<<nb, tb, 0, stream>>>(ref, tar, dsA, dsB, rain);
  k_blur2<<<dim3(8, BATCH, 2), tb, 0, stream>>>(dsA, dsB, prevW, currW,
                                                nullptr, nullptr, nullptr, nullptr);
  k_cost_flow<<<dim3(LR/TH, BATCH, 2), 512, 0, stream>>>(prevW, currW, cKa, cKb);
  k_blur2<<<dim3(8, BATCH, 2), tb, 0, stream>>>(nullptr, nullptr, fxb, fyb,
                                                rain, rain, cKa, cKb);
  k_loss<<<2048, tb, 0, stream>>>(pred, tar, ref, fxb, fyb, out);
}

// Round 5
// 213.738 us; speedup vs baseline: 7.9806x; 7.9806x over previous
//
#include <hip/hip_runtime.h>
#include <math.h>

#define BATCH 16
#define HR 512
#define LR 128
#define N_LR (BATCH*LR*LR)   // 262144
#define N_HR (BATCH*HR*HR)   // 4194304
#define NSH 13
#define NSHIFT 169
#define TH 8                 // output rows per k_cost block
#define NW 8                 // waves per k_cost block
#define CPAD 144             // 6 left pad + 128 + 10 right pad (cols pre-clamped)
#define CROWS 40             // curr rows r0-16 .. r0+23 (clamped)

__device__ __forceinline__ int clampi(int v, int lo, int hi){ return v<lo?lo:(v>hi?hi:v); }

// 7-tap gaussian, sigma=1, normalized; t compile-time under unroll -> folds.
__device__ __forceinline__ float gk(int t){
  const float e1 = 0.60653065971263342f;
  const float e2 = 0.13533528323661270f;
  const float e3 = 0.011108996538242306f;
  const float norm = 1.0f/(1.0f + 2.0f*(e1+e2+e3));
  int a = t < 0 ? -t : t;
  float v = (a==0) ? 1.0f : (a==1 ? e1 : (a==2 ? e2 : e3));
  return v*norm;
}

// log1p(max(.,0)) + exact 4:1 downsample; dense float4 row loads (use .y/.z).
__global__ void k_downsample(const float* __restrict__ ref, const float* __restrict__ tar,
                             float* __restrict__ wref, float* __restrict__ wtar,
                             float* __restrict__ rain){
  int i = blockIdx.x*blockDim.x + threadIdx.x;
  if (i >= N_LR) return;
  int x = i & (LR-1); int y = (i >> 7) & (LR-1); int b = i >> 14;
  int base = b*HR*HR + (4*y+1)*HR + 4*x;      // 16B aligned
  float4 r1 = *(const float4*)(ref + base);
  float4 r2 = *(const float4*)(ref + base + HR);
  float4 t1 = *(const float4*)(tar + base);
  float4 t2 = *(const float4*)(tar + base + HR);
  float r00=r1.y, r01=r1.z, r10=r2.y, r11=r2.z;
  float t00=t1.y, t01=t1.z, t10=t2.y, t11=t2.z;
  wref[i] = 0.25f*(log1pf(fmaxf(r00,0.f))+log1pf(fmaxf(r01,0.f))
                 +log1pf(fmaxf(r10,0.f))+log1pf(fmaxf(r11,0.f)));
  wtar[i] = 0.25f*(log1pf(fmaxf(t00,0.f))+log1pf(fmaxf(t01,0.f))
                 +log1pf(fmaxf(t10,0.f))+log1pf(fmaxf(t11,0.f)));
  rain[i] = (0.25f*(t00+t01+t10+t11) >= 0.1f) ? 1.0f : 0.0f;
}

// Fused separable 7x7 edge-clamped gaussian; blockIdx.z selects field pair.
// Cost-decode mode (cA != nullptr): staging input is the cross-z merged argmin
// key; z=0 decodes fx = (s%13-6)*rain, z=1 decodes fy = (s/13-6)*rain —
// bit-exact vs. the old materialized fx/fy (integer-valued float * {0,1}).
__global__ void k_blur2(const float* __restrict__ in0, const float* __restrict__ in1,
                        float* __restrict__ out0, float* __restrict__ out1,
                        const float* __restrict__ m0, const float* __restrict__ m1,
                        const unsigned long long* __restrict__ cA,
                        const unsigned long long* __restrict__ cB){
  const int z = blockIdx.z;
  float* out       = z ? out1 : out0;
  const float* msk = z ? m1 : m0;
  const int r0 = blockIdx.x * 16;
  const int bb = blockIdx.y;
  const int tid = threadIdx.x;
  __shared__ float raw[22][LR];
  __shared__ float hb[22][LR];
  for (int idx = tid; idx < 22*LR; idx += 256){
    int lr = idx >> 7, c = idx & (LR-1);
    int gr = clampi(r0 - 3 + lr, 0, LR-1);
    int gi = (bb<<14) + (gr<<7) + c;
    float v;
    if (cA){
      unsigned long long kk0 = cA[gi], kk1 = cB[gi];
      unsigned long long kk = (kk1 < kk0) ? kk1 : kk0;
      int sv = (int)(kk & 0xffffffffULL);
      int dv = z ? (sv / NSH - 6) : (sv % NSH - 6);
      v = (float)dv * msk[gi];
    } else {
      const float* in = z ? in1 : in0;
      v = in[gi];
    }
    raw[lr][c] = v;
  }
  __syncthreads();
  for (int idx = tid; idx < 22*LR; idx += 256){
    int lr = idx >> 7, c = idx & (LR-1);
    float s = 0.f;
    #pragma unroll
    for (int t=-3;t<=3;++t) s += gk(t)*raw[lr][clampi(c+t,0,LR-1)];
    hb[lr][c] = s;
  }
  __syncthreads();
  for (int idx = tid; idx < 16*LR; idx += 256){
    int lr = idx >> 7, c = idx & (LR-1);
    int i = r0 + lr;
    float s = 0.f;
    #pragma unroll
    for (int t=-3;t<=3;++t) s += gk(t)*hb[clampi(i+t,0,LR-1) - (r0-3)][c];
    int gi = (bb<<14) + (i<<7) + c;
    if (msk) s *= msk[gi];
    out[gi] = s;
  }
}

// --- DPP wave64 inclusive prefix (rocPRIM scan sequence), pure VALU ---
template<int CTRL, int RM>
__device__ __forceinline__ float dpp_mov0(float x){
  return __int_as_float(__builtin_amdgcn_update_dpp(0, __float_as_int(x), CTRL, RM, 0xF, true));
}
__device__ __forceinline__ float prefix64(float x){
  x += dpp_mov0<0x111,0xF>(x);   // row_shr:1
  x += dpp_mov0<0x112,0xF>(x);   // row_shr:2
  x += dpp_mov0<0x114,0xF>(x);   // row_shr:4
  x += dpp_mov0<0x118,0xF>(x);   // row_shr:8
  x += dpp_mov0<0x142,0xA>(x);   // row_bcast:15 -> rows 1,3
  x += dpp_mov0<0x143,0xC>(x);   // row_bcast:31 -> rows 2,3
  return x;
}
__device__ __forceinline__ float bperm(int addr4, float v){
  return __int_as_float(__builtin_amdgcn_ds_bpermute(addr4, __float_as_int(v)));
}

struct TapCtx { int ia0, ib0, ia1, ib1; bool lb0ok, selA, selB; };

// Horizontal 21-tap zero-pad box via prefix-diff over the 128-col row held as
// (col=lane in v0, col=lane+64 in v1); register argmin update.
// pg1 = pf1 + T0 pre-folds the two conditional +T0 tap fixups (bit-identical:
// bperm moves bits exactly, so adding T0 before the permute on the pf1-sourced
// lanes equals the old post-permute conditional add for every lane case).
__device__ __forceinline__ void horiz_update(const TapCtx& tc, float v0, float v1, int s,
                                             unsigned long long& k0ref, unsigned long long& k1ref){
  float pf0 = prefix64(v0);
  float pf1 = prefix64(v1);
  float T0 = __int_as_float(__builtin_amdgcn_readlane(__float_as_int(pf0), 63));
  float pg1 = pf1 + T0;
  float va = tc.selA ? pf0 : pg1;      // src lane t: t>=10 ? pf0 : pg1
  float vb = tc.selB ? pf0 : pg1;      // src lane t: t>=53 ? pf0 : pg1
  float a0 = bperm(tc.ia0, va);                        // P(x+10), x=lane
  float b0 = tc.lb0ok ? bperm(tc.ib0, pf0) : 0.f;      // P(x-11) or 0
  float a1 = bperm(tc.ia1, pg1);                       // P(min(x+10,127)), x=lane+64
  float b1 = bperm(tc.ib1, vb);                        // P(x-11), x=lane+64
  float c0 = fmaxf((a0 - b0) * (1.0f/441.0f), 0.f);
  float c1 = fmaxf((a1 - b1) * (1.0f/441.0f), 0.f);
  unsigned long long k0 = ((unsigned long long)__float_as_uint(c0) << 32) | (unsigned)s;
  unsigned long long k1 = ((unsigned long long)__float_as_uint(c1) << 32) | (unsigned)s;
  if (k0 < k0ref) k0ref = k0;
  if (k1 < k1ref) k1ref = k1;
}

// Per-wave cost walk over contiguous shift range [t_lo, t_hi) in dy-major order
// (so s == t directly). q rows come straight from the column-padded LDS tile;
// vertical 21-row box built per shift, slid across the 8 output rows.
// EDGE=false (interior tiles): no row guards at all.
template<bool EDGE>
__device__ __forceinline__ void cost_loop(int r0, int lane, int t_lo, int t_hi,
    const float (*cT)[CPAD], const float* p0, const float* p1, const TapCtx& tc,
    unsigned long long* bk0, unsigned long long* bk1){
  #pragma unroll 1
  for (int t = t_lo; t < t_hi; ++t){
    const int dyi = t / NSH;
    const int dxi = t - dyi*NSH;
    const int pc = lane + dxi;                 // padded col = (x + dx) + 6, x=lane
    float v0 = 0.f, v1 = 0.f;
    #pragma unroll
    for (int wr = 0; wr <= 20; ++wr){
      if (!EDGE || ((r0 - 10 + wr) >= 0 && (r0 - 10 + wr) < LR)){
        float d0 = p0[wr] - cT[dyi + wr][pc];
        float d1 = p1[wr] - cT[dyi + wr][pc + 64];
        v0 = fmaf(d0, d0, v0);
        v1 = fmaf(d1, d1, v1);
      }
    }
    horiz_update(tc, v0, v1, t, bk0[0], bk1[0]);
    #pragma unroll
    for (int io = 1; io < TH; ++io){
      const int wrA = io + 20;                 // add leading row
      if (!EDGE || ((r0 - 10 + wrA) < LR)){
        float d0 = p0[wrA] - cT[dyi + wrA][pc];
        float d1 = p1[wrA] - cT[dyi + wrA][pc + 64];
        v0 = fmaf(d0, d0, v0);
        v1 = fmaf(d1, d1, v1);
      }
      const int wrS = io - 1;                  // subtract trailing row
      if (!EDGE || ((r0 - 10 + wrS) >= 0)){
        float d0 = p0[wrS] - cT[dyi + wrS][pc];
        float d1 = p1[wrS] - cT[dyi + wrS][pc + 64];
        v0 = fmaf(-d0, d0, v0);
        v1 = fmaf(-d1, d1, v1);
      }
      horiz_update(tc, v0, v1, t, bk0[io], bk1[io]);
    }
  }
}

// Block = (row-tile of 8, batch, shift-half). blockIdx.z splits the 169 shifts
// 85/84 -> 512 blocks = 2 blocks/CU (LDS-limited: 55.8KB*2 < 160KB) = 4
// waves/SIMD for latency hiding. __launch_bounds__(512,2): the 2nd arg is
// min BLOCKS/CU (CUDA semantics — (512,4) capped VGPRs at 64 and spilled
// catastrophically in round 4; (512,2) gives the proven 128-VGPR cap).
// Each z-block writes its fully merged u64 argmin keys to its own buffer
// (plain stores, no atomics); cross-z min + flow decode fused into k_blur2.
__global__ void __launch_bounds__(512, 2)
k_cost_flow(const float* __restrict__ prev, const float* __restrict__ curr,
            unsigned long long* __restrict__ c0out, unsigned long long* __restrict__ c1out){
  const int r0 = blockIdx.x * TH;
  const int bb = blockIdx.y;
  const int z  = blockIdx.z;
  const int tid = threadIdx.x;
  const int w = tid >> 6, lane = tid & 63;
  const float* P = prev + (bb<<14);
  const float* C = curr + (bb<<14);

  __shared__ float currT[CROWS][CPAD];            // 22.5 KB
  __shared__ unsigned long long mg[4][TH*LR];     // merge slots, 32 KB

  for (int idx = tid; idx < CROWS*CPAD; idx += 512){
    int lr = idx / CPAD, j = idx - lr*CPAD;
    int gr = clampi(r0 - 16 + lr, 0, LR-1);
    int gc = clampi(j - 6, 0, LR-1);
    currT[lr][j] = C[(gr<<7) + gc];
  }

  // prev rows r0-10..r0+17 at cols (lane, lane+64), zero out of range (unused there)
  float p0[28], p1[28];
  #pragma unroll
  for (int wr = 0; wr < 28; ++wr){
    int gr = r0 - 10 + wr;
    if (gr >= 0 && gr < LR){ p0[wr] = P[(gr<<7) + lane]; p1[wr] = P[(gr<<7) + lane + 64]; }
    else                   { p0[wr] = 0.f; p1[wr] = 0.f; }
  }
  __syncthreads();

  unsigned long long bk0[TH], bk1[TH];
  #pragma unroll
  for (int io = 0; io < TH; ++io){ bk0[io] = ~0ULL; bk1[io] = ~0ULL; }

  TapCtx tc;
  tc.ia0 = ((lane + 10) & 63) << 2;
  tc.ib0 = ((lane - 11) & 63) << 2;
  tc.ia1 = (min(lane + 10, 63)) << 2;
  tc.ib1 = ((lane + 53) & 63) << 2;
  tc.lb0ok = (lane >= 11);
  tc.selA  = (lane >= 10);
  tc.selB  = (lane >= 53);

  const int base = z ? 85 : 0;                // z=0: t 0..84, z=1: t 85..168
  const int cnt  = z ? 84 : 85;
  const int t_lo = base + (cnt * w) / NW;
  const int t_hi = base + (cnt * (w+1)) / NW;

  const bool interior = (r0 >= 10) && (r0 + TH + 9 < LR);
  if (interior) cost_loop<false>(r0, lane, t_lo, t_hi, currT, p0, p1, tc, bk0, bk1);
  else          cost_loop<true >(r0, lane, t_lo, t_hi, currT, p0, p1, tc, bk0, bk1);

  // slotted tree merge: slot g=w&3, waves 0-3 write, 4-7 merge, then 4-slot min
  __syncthreads();
  const int g = w & 3;
  if (w < 4){
    #pragma unroll
    for (int io = 0; io < TH; ++io){
      mg[g][io*LR + lane]      = bk0[io];
      mg[g][io*LR + lane + 64] = bk1[io];
    }
  }
  __syncthreads();
  if (w >= 4){
    #pragma unroll
    for (int io = 0; io < TH; ++io){
      unsigned long long m0 = mg[g][io*LR + lane];
      unsigned long long m1 = mg[g][io*LR + lane + 64];
      mg[g][io*LR + lane]      = (bk0[io] < m0) ? bk0[io] : m0;
      mg[g][io*LR + lane + 64] = (bk1[io] < m1) ? bk1[io] : m1;
    }
  }
  __syncthreads();
  unsigned long long* cz = z ? c1out : c0out;
  for (int p = tid; p < TH*LR; p += 512){
    unsigned long long k  = mg[0][p];
    unsigned long long k1 = mg[1][p]; if (k1 < k) k = k1;
    unsigned long long k2 = mg[2][p]; if (k2 < k) k = k2;
    unsigned long long k3 = mg[3][p]; if (k3 < k) k = k3;
    cz[(bb<<14) + (r0<<7) + p] = k;
  }
}

// Fused: flow upsample (x4), warp of ref (border bilinear), Huber+mask, mean-reduce.
// Thread = 2 groups of 4 px; 12 shared flow loads/group (wx,wy are exact constants
// per x&3/y&3); per-px bilinear keeps round-3 operand order exactly.
__global__ void __launch_bounds__(256)
k_loss(const float* __restrict__ pred, const float* __restrict__ tar,
       const float* __restrict__ ref, const float* __restrict__ fxb,
       const float* __restrict__ fyb, float* __restrict__ out){
  const int t0 = blockIdx.x*256 + threadIdx.x;   // 0..524287
  float acc = 0.f;
  #pragma unroll
  for (int it = 0; it < 2; ++it){
    const int gq  = t0 + it*524288;
    const int b   = gq >> 16;
    const int rem = gq & 65535;
    const int y   = rem >> 7;
    const int m   = rem & 127;
    const int n = y >> 2, ky = y & 3;
    int y0; float wy;
    if (ky < 2){ y0 = max(n-1, 0); wy = (n >= 1) ? (ky == 0 ? 0.625f : 0.875f) : 0.f; }
    else       { y0 = n;           wy = (ky == 2) ? 0.125f : 0.375f; }
    const int y1 = min(y0+1, LR-1);
    const int lb = b << 14;
    const float* FxR0 = fxb + lb + (y0<<7);
    const float* FxR1 = fxb + lb + (y1<<7);
    const float* FyR0 = fyb + lb + (y0<<7);
    const float* FyR1 = fyb + lb + (y1<<7);
    const int cA = max(m-1, 0), cB = m, cC = min(m+1, LR-1);
    float xA0 = FxR0[cA], xB0 = FxR0[cB], xC0 = FxR0[cC];
    float xA1 = FxR1[cA], xB1 = FxR1[cB], xC1 = FxR1[cC];
    float yA0 = FyR0[cA], yB0 = FyR0[cB], yC0 = FyR0[cC];
    float yA1 = FyR1[cA], yB1 = FyR1[cB], yC1 = FyR1[cC];
    const bool mh = (m >= 1);
    const int hb = (b<<18) + (y<<9) + (m<<2);
    float4 pd = *(const float4*)(pred + hb);
    float4 td = *(const float4*)(tar + hb);
    const float* R = ref + (b<<18);
    const float wy1 = 1.f - wy;
    #pragma unroll
    for (int k = 0; k < 4; ++k){
      float wx;
      float lo0, hi0, lo1, hi1, flo0, fhi0, flo1, fhi1;
      if (k < 2){
        wx = mh ? (k == 0 ? 0.625f : 0.875f) : 0.f;
        lo0 = mh ? xA0 : xB0;  hi0 = mh ? xB0 : xC0;
        lo1 = mh ? xA1 : xB1;  hi1 = mh ? xB1 : xC1;
        flo0 = mh ? yA0 : yB0; fhi0 = mh ? yB0 : yC0;
        flo1 = mh ? yA1 : yB1; fhi1 = mh ? yB1 : yC1;
      } else {
        wx = (k == 2) ? 0.125f : 0.375f;
        lo0 = xB0;  hi0 = xC0;  lo1 = xB1;  hi1 = xC1;
        flo0 = yB0; fhi0 = yC0; flo1 = yB1; fhi1 = yC1;
      }
      const float w00 = wy1*(1.f-wx), w01 = wy1*wx, w10 = wy*(1.f-wx), w11 = wy*wx;
      const float fxv = 4.f*(w00*lo0 + w01*hi0 + w10*lo1 + w11*hi1);
      const float fyv = 4.f*(w00*flo0 + w01*fhi0 + w10*flo1 + w11*fhi1);
      const int x = (m<<2) + k;
      float ix = fminf(fmaxf((float)x - fxv, 0.f), (float)(HR-1));
      float iy = fminf(fmaxf((float)y - fyv, 0.f), (float)(HR-1));
      int gx0 = (int)ix; int gx1 = min(gx0+1, HR-1); float gwx = ix - (float)gx0;
      int gy0 = (int)iy; int gy1 = min(gy0+1, HR-1); float gwy = iy - (float)gy0;
      float v00 = R[(gy0<<9)+gx0], v01 = R[(gy0<<9)+gx1];
      float v10 = R[(gy1<<9)+gx0], v11 = R[(gy1<<9)+gx1];
      float tt = v00*(1.f-gwy)*(1.f-gwx) + v01*(1.f-gwy)*gwx
               + v10*gwy*(1.f-gwx)       + v11*gwy*gwx;
      float teacher = fmaxf(tt, 0.f);
      float pk = ((const float*)&pd)[k];
      float tk = ((const float*)&td)[k];
      float d  = pk - teacher;
      float ad = fabsf(d);
      float l  = ad < 0.2f ? 0.5f*d*d : 0.2f*(ad - 0.1f);
      float mm = (teacher > 0.05f || tk > 0.05f) ? 1.f : 0.f;
      acc += l*mm;
    }
  }
  acc *= (1.0f/(float)N_HR);
  #pragma unroll
  for (int o = 32; o > 0; o >>= 1) acc += __shfl_down(acc, o, 64);
  __shared__ float wsum[4];
  int lane = threadIdx.x & 63, wv = threadIdx.x >> 6;
  if (lane == 0) wsum[wv] = acc;
  __syncthreads();
  if (threadIdx.x == 0) atomicAdd(out, wsum[0]+wsum[1]+wsum[2]+wsum[3]);
}

extern "C" void kernel_launch(void* const* d_in, const int* in_sizes, int n_in,
                              void* d_out, int out_size, void* d_ws, size_t ws_size,
                              hipStream_t stream){
  const float* pred = (const float*)d_in[0];
  const float* tar  = (const float*)d_in[1];
  const float* ref  = (const float*)d_in[2];
  float* out = (float*)d_out;
  float* w = (float*)d_ws;
  float* prevW = w + 0*N_LR;
  float* currW = w + 1*N_LR;
  float* rain  = w + 2*N_LR;
  float* fxb   = w + 3*N_LR;
  float* fyb   = w + 4*N_LR;
  float* dsA   = w + 5*N_LR;   // wref_ds (dead after blur#1)
  float* dsB   = w + 6*N_LR;   // wtar_ds (dead after blur#1)
  // u64 argmin-key buffers: cKa overlays dsA+dsB (2*N_LR floats = N_LR u64),
  // cKb extends the workspace (peak 9*N_LR floats = 9 MB).
  unsigned long long* cKa = (unsigned long long*)(w + 5*N_LR);
  unsigned long long* cKb = (unsigned long long*)(w + 7*N_LR);

  hipMemsetAsync(d_out, 0, sizeof(float), stream);

  const int tb = 256, nb = (N_LR + tb - 1)/tb;
  k_downsample<<<nb, tb, 0, stream>>>(ref, tar, dsA, dsB, rain);
  k_blur2<<<dim3(8, BATCH, 2), tb, 0, stream>>>(dsA, dsB, prevW, currW,
                                                nullptr, nullptr, nullptr, nullptr);
  k_cost_flow<<<dim3(LR/TH, BATCH, 2), 512, 0, stream>>>(prevW, currW, cKa, cKb);
  k_blur2<<<dim3(8, BATCH, 2), tb, 0, stream>>>(nullptr, nullptr, fxb, fyb,
                                                rain, rain, cKa, cKb);
  k_loss<<<2048, tb, 0, stream>>>(pred, tar, ref, fxb, fyb, out);
}

// Round 6
// 194.581 us; speedup vs baseline: 8.7663x; 1.0984x over previous
//
#include <hip/hip_runtime.h>
#include <math.h>

#define BATCH 16
#define HR 512
#define LR 128
#define N_LR (BATCH*LR*LR)   // 262144
#define N_HR (BATCH*HR*HR)   // 4194304
#define NSH 13
#define NSHIFT 169
#define TH 8                 // output rows per k_cost block
#define NW 8                 // waves per k_cost block

__device__ __forceinline__ int clampi(int v, int lo, int hi){ return v<lo?lo:(v>hi?hi:v); }

// 7-tap gaussian, sigma=1, normalized; t compile-time under unroll -> folds.
__device__ __forceinline__ float gk(int t){
  const float e1 = 0.60653065971263342f;
  const float e2 = 0.13533528323661270f;
  const float e3 = 0.011108996538242306f;
  const float norm = 1.0f/(1.0f + 2.0f*(e1+e2+e3));
  int a = t < 0 ? -t : t;
  float v = (a==0) ? 1.0f : (a==1 ? e1 : (a==2 ? e2 : e3));
  return v*norm;
}

// log1p(max(.,0)) + exact 4:1 downsample; dense float4 row loads (use .y/.z).
__global__ void k_downsample(const float* __restrict__ ref, const float* __restrict__ tar,
                             float* __restrict__ wref, float* __restrict__ wtar,
                             float* __restrict__ rain){
  int i = blockIdx.x*blockDim.x + threadIdx.x;
  if (i >= N_LR) return;
  int x = i & (LR-1); int y = (i >> 7) & (LR-1); int b = i >> 14;
  int base = b*HR*HR + (4*y+1)*HR + 4*x;      // 16B aligned
  float4 r1 = *(const float4*)(ref + base);
  float4 r2 = *(const float4*)(ref + base + HR);
  float4 t1 = *(const float4*)(tar + base);
  float4 t2 = *(const float4*)(tar + base + HR);
  float r00=r1.y, r01=r1.z, r10=r2.y, r11=r2.z;
  float t00=t1.y, t01=t1.z, t10=t2.y, t11=t2.z;
  wref[i] = 0.25f*(log1pf(fmaxf(r00,0.f))+log1pf(fmaxf(r01,0.f))
                 +log1pf(fmaxf(r10,0.f))+log1pf(fmaxf(r11,0.f)));
  wtar[i] = 0.25f*(log1pf(fmaxf(t00,0.f))+log1pf(fmaxf(t01,0.f))
                 +log1pf(fmaxf(t10,0.f))+log1pf(fmaxf(t11,0.f)));
  rain[i] = (0.25f*(t00+t01+t10+t11) >= 0.1f) ? 1.0f : 0.0f;
}

// Fused separable 7x7 edge-clamped gaussian; blockIdx.z selects field pair.
// Cost-decode mode (cA != nullptr): staging input is the cross-z merged argmin
// key; z=0 decodes fx = (s%13-6)*rain, z=1 decodes fy = (s/13-6)*rain —
// bit-exact vs. materialized fx/fy (integer-valued float * {0,1}). [r5-verified]
__global__ void k_blur2(const float* __restrict__ in0, const float* __restrict__ in1,
                        float* __restrict__ out0, float* __restrict__ out1,
                        const float* __restrict__ m0, const float* __restrict__ m1,
                        const unsigned long long* __restrict__ cA,
                        const unsigned long long* __restrict__ cB){
  const int z = blockIdx.z;
  float* out       = z ? out1 : out0;
  const float* msk = z ? m1 : m0;
  const int r0 = blockIdx.x * 16;
  const int bb = blockIdx.y;
  const int tid = threadIdx.x;
  __shared__ float raw[22][LR];
  __shared__ float hb[22][LR];
  for (int idx = tid; idx < 22*LR; idx += 256){
    int lr = idx >> 7, c = idx & (LR-1);
    int gr = clampi(r0 - 3 + lr, 0, LR-1);
    int gi = (bb<<14) + (gr<<7) + c;
    float v;
    if (cA){
      unsigned long long kk0 = cA[gi], kk1 = cB[gi];
      unsigned long long kk = (kk1 < kk0) ? kk1 : kk0;
      int sv = (int)(kk & 0xffffffffULL);
      int dv = z ? (sv / NSH - 6) : (sv % NSH - 6);
      v = (float)dv * msk[gi];
    } else {
      const float* in = z ? in1 : in0;
      v = in[gi];
    }
    raw[lr][c] = v;
  }
  __syncthreads();
  for (int idx = tid; idx < 22*LR; idx += 256){
    int lr = idx >> 7, c = idx & (LR-1);
    float s = 0.f;
    #pragma unroll
    for (int t=-3;t<=3;++t) s += gk(t)*raw[lr][clampi(c+t,0,LR-1)];
    hb[lr][c] = s;
  }
  __syncthreads();
  for (int idx = tid; idx < 16*LR; idx += 256){
    int lr = idx >> 7, c = idx & (LR-1);
    int i = r0 + lr;
    float s = 0.f;
    #pragma unroll
    for (int t=-3;t<=3;++t) s += gk(t)*hb[clampi(i+t,0,LR-1) - (r0-3)][c];
    int gi = (bb<<14) + (i<<7) + c;
    if (msk) s *= msk[gi];
    out[gi] = s;
  }
}

// --- DPP wave64 inclusive prefix (rocPRIM scan sequence), pure VALU ---
template<int CTRL, int RM>
__device__ __forceinline__ float dpp_mov0(float x){
  return __int_as_float(__builtin_amdgcn_update_dpp(0, __float_as_int(x), CTRL, RM, 0xF, true));
}
__device__ __forceinline__ float prefix64(float x){
  x += dpp_mov0<0x111,0xF>(x);   // row_shr:1
  x += dpp_mov0<0x112,0xF>(x);   // row_shr:2
  x += dpp_mov0<0x114,0xF>(x);   // row_shr:4
  x += dpp_mov0<0x118,0xF>(x);   // row_shr:8
  x += dpp_mov0<0x142,0xA>(x);   // row_bcast:15 -> rows 1,3
  x += dpp_mov0<0x143,0xC>(x);   // row_bcast:31 -> rows 2,3
  return x;
}
__device__ __forceinline__ float bperm(int addr4, float v){
  return __int_as_float(__builtin_amdgcn_ds_bpermute(addr4, __float_as_int(v)));
}

struct TapCtx { int ia0, ib0, ia1, ib1; bool lb0ok, selA, selB; };

// Horizontal 21-tap zero-pad box via prefix-diff over the 128-col row held as
// (col=lane in v0, col=lane+64 in v1); register argmin update.
// pg1 = pf1 + T0 pre-folds the two conditional +T0 tap fixups (bit-identical:
// bperm moves bits exactly, so adding T0 before the permute on the pf1-sourced
// lanes equals the old post-permute conditional add for every lane case).
// [r3/r5-verified]
__device__ __forceinline__ void horiz_update(const TapCtx& tc, float v0, float v1, int s,
                                             unsigned long long& k0ref, unsigned long long& k1ref){
  float pf0 = prefix64(v0);
  float pf1 = prefix64(v1);
  float T0 = __int_as_float(__builtin_amdgcn_readlane(__float_as_int(pf0), 63));
  float pg1 = pf1 + T0;
  float va = tc.selA ? pf0 : pg1;      // src lane t: t>=10 ? pf0 : pg1
  float vb = tc.selB ? pf0 : pg1;      // src lane t: t>=53 ? pf0 : pg1
  float a0 = bperm(tc.ia0, va);                        // P(x+10), x=lane
  float b0 = tc.lb0ok ? bperm(tc.ib0, pf0) : 0.f;      // P(x-11) or 0
  float a1 = bperm(tc.ia1, pg1);                       // P(min(x+10,127)), x=lane+64
  float b1 = bperm(tc.ib1, vb);                        // P(x-11), x=lane+64
  float c0 = fmaxf((a0 - b0) * (1.0f/441.0f), 0.f);
  float c1 = fmaxf((a1 - b1) * (1.0f/441.0f), 0.f);
  unsigned long long k0 = ((unsigned long long)__float_as_uint(c0) << 32) | (unsigned)s;
  unsigned long long k1 = ((unsigned long long)__float_as_uint(c1) << 32) | (unsigned)s;
  if (k0 < k0ref) k0ref = k0;
  if (k1 < k1ref) k1ref = k1;
}

// Block = (row-tile of 8, batch, shift-half). Round-0 proven inner structure:
// prev rows in regs, curr 28-row REGISTER window per dx-group slid one row per
// dy (dx-major walk) — the register window doubles as latency-hiding filler
// (r3/r5's LDS-q variant was slower despite fewer VALU ops). blockIdx.z splits
// the 169 shifts 85/84. LDS cut to 28 KB (currT 20 KB + single 8 KB u64
// ds_min merge slot instead of the 32 KB slotted tree) so 2 blocks/CU
// co-reside under ANY LDS-pool hypothesis -> 4 waves/SIMD. Keys out per z
// (plain stores); cross-z min + flow decode fused into k_blur2 [r5-verified].
__global__ void __launch_bounds__(512, 2)
k_cost_flow(const float* __restrict__ prev, const float* __restrict__ curr,
            unsigned long long* __restrict__ c0out, unsigned long long* __restrict__ c1out){
  const int r0 = blockIdx.x * TH;
  const int bb = blockIdx.y;
  const int z  = blockIdx.z;
  const int tid = threadIdx.x;
  const int w = tid >> 6, lane = tid & 63;
  const float* P = prev + (bb<<14);
  const float* C = curr + (bb<<14);

  __shared__ float currT[40][LR];                 // rows r0-16..r0+23 (clamped), 20 KB
  __shared__ unsigned long long mgA[TH*LR];       // single merge slot, 8 KB

  for (int idx = tid; idx < 40*LR; idx += 512){
    int lr = idx >> 7, c = idx & (LR-1);
    int gr = clampi(r0 - 16 + lr, 0, LR-1);
    currT[lr][c] = C[(gr<<7) + c];
  }
  for (int p = tid; p < TH*LR; p += 512) mgA[p] = ~0ULL;

  // prev rows r0-10..r0+17 at cols (lane, lane+64), zero-pad out of range
  float p0[28], p1[28];
  #pragma unroll
  for (int wr = 0; wr < 28; ++wr){
    int gr = r0 - 10 + wr;
    if (gr >= 0 && gr < LR){ p0[wr] = P[(gr<<7) + lane]; p1[wr] = P[(gr<<7) + lane + 64]; }
    else                   { p0[wr] = 0.f; p1[wr] = 0.f; }
  }
  __syncthreads();

  unsigned long long bk0[TH], bk1[TH];
  #pragma unroll
  for (int io = 0; io < TH; ++io){ bk0[io] = ~0ULL; bk1[io] = ~0ULL; }

  TapCtx tc;
  tc.ia0 = ((lane + 10) & 63) << 2;
  tc.ib0 = ((lane - 11) & 63) << 2;
  tc.ia1 = (min(lane + 10, 63)) << 2;
  tc.ib1 = ((lane + 53) & 63) << 2;
  tc.lb0ok = (lane >= 11);
  tc.selA  = (lane >= 10);
  tc.selB  = (lane >= 53);

  const int base = z ? 85 : 0;                // z=0: t 0..84, z=1: t 85..168
  const int cnt  = z ? 84 : 85;
  const int t_lo = base + (cnt * w) / NW;
  const int t_hi = base + (cnt * (w+1)) / NW;

  int t = t_lo;
  while (t < t_hi){
    const int dxi  = t / NSH;                    // dx-major walk: t = dxi*13 + dyi
    const int dyi0 = t - dxi*NSH;
    const int ndy  = min(NSH - dyi0, t_hi - t);
    const int dx   = dxi - 6;
    const int c0   = clampi(lane + dx, 0, LR-1);
    const int c1   = clampi(lane + 64 + dx, 0, LR-1);
    // curr register window: rows dyi0..dyi0+27 of currT
    float q0[28], q1[28];
    #pragma unroll
    for (int wr = 0; wr < 28; ++wr){
      q0[wr] = currT[wr + dyi0][c0];
      q1[wr] = currT[wr + dyi0][c1];
    }
    int s = dyi0*NSH + dxi;                      // reference (dy-major) shift index
    for (int rep = 0; rep < ndy; ++rep){
      float v0 = 0.f, v1 = 0.f;
      #pragma unroll
      for (int wr = 0; wr <= 20; ++wr){
        if (r0 - 10 + wr >= 0 && r0 - 10 + wr < LR){   // wave-uniform
          float d0 = p0[wr] - q0[wr];
          float d1 = p1[wr] - q1[wr];
          v0 = fmaf(d0, d0, v0);
          v1 = fmaf(d1, d1, v1);
        }
      }
      horiz_update(tc, v0, v1, s, bk0[0], bk1[0]);
      #pragma unroll
      for (int io = 1; io < TH; ++io){
        {
          const int wrA = io + 20;                     // add leading row
          if (r0 - 10 + wrA < LR){
            float d0 = p0[wrA] - q0[wrA];
            float d1 = p1[wrA] - q1[wrA];
            v0 = fmaf(d0, d0, v0);
            v1 = fmaf(d1, d1, v1);
          }
          const int wrS = io - 1;                      // subtract trailing row
          if (r0 - 10 + wrS >= 0){
            float d0 = p0[wrS] - q0[wrS];
            float d1 = p1[wrS] - q1[wrS];
            v0 = fmaf(-d0, d0, v0);
            v1 = fmaf(-d1, d1, v1);
          }
        }
        horiz_update(tc, v0, v1, s, bk0[io], bk1[io]);
      }
      if (rep < ndy - 1){
        #pragma unroll
        for (int wr = 0; wr < 27; ++wr){ q0[wr] = q0[wr+1]; q1[wr] = q1[wr+1]; }
        q0[27] = currT[dyi0 + rep + 28][c0];
        q1[27] = currT[dyi0 + rep + 28][c1];
      }
      s += NSH;
    }
    t += ndy;
  }

  // cross-wave merge: lexicographic (cost, s) u64 min via LDS atomics.
  // mgA init completed before the pre-loop barrier, so waves merge as they
  // finish; one barrier before readback.
  #pragma unroll
  for (int io = 0; io < TH; ++io){
    atomicMin(&mgA[io*LR + lane],      bk0[io]);
    atomicMin(&mgA[io*LR + lane + 64], bk1[io]);
  }
  __syncthreads();
  unsigned long long* cz = z ? c1out : c0out;
  for (int p = tid; p < TH*LR; p += 512){
    cz[(bb<<14) + (r0<<7) + p] = mgA[p];
  }
}

// Fused: flow upsample (x4), warp of ref (border bilinear), Huber+mask, mean-reduce.
// Thread = 2 groups of 4 px; 12 shared flow loads/group (wx,wy are exact constants
// per x&3/y&3); per-px bilinear keeps round-3 operand order exactly.
__global__ void __launch_bounds__(256)
k_loss(const float* __restrict__ pred, const float* __restrict__ tar,
       const float* __restrict__ ref, const float* __restrict__ fxb,
       const float* __restrict__ fyb, float* __restrict__ out){
  const int t0 = blockIdx.x*256 + threadIdx.x;   // 0..524287
  float acc = 0.f;
  #pragma unroll
  for (int it = 0; it < 2; ++it){
    const int gq  = t0 + it*524288;
    const int b   = gq >> 16;
    const int rem = gq & 65535;
    const int y   = rem >> 7;
    const int m   = rem & 127;
    const int n = y >> 2, ky = y & 3;
    int y0; float wy;
    if (ky < 2){ y0 = max(n-1, 0); wy = (n >= 1) ? (ky == 0 ? 0.625f : 0.875f) : 0.f; }
    else       { y0 = n;           wy = (ky == 2) ? 0.125f : 0.375f; }
    const int y1 = min(y0+1, LR-1);
    const int lb = b << 14;
    const float* FxR0 = fxb + lb + (y0<<7);
    const float* FxR1 = fxb + lb + (y1<<7);
    const float* FyR0 = fyb + lb + (y0<<7);
    const float* FyR1 = fyb + lb + (y1<<7);
    const int cA = max(m-1, 0), cB = m, cC = min(m+1, LR-1);
    float xA0 = FxR0[cA], xB0 = FxR0[cB], xC0 = FxR0[cC];
    float xA1 = FxR1[cA], xB1 = FxR1[cB], xC1 = FxR1[cC];
    float yA0 = FyR0[cA], yB0 = FyR0[cB], yC0 = FyR0[cC];
    float yA1 = FyR1[cA], yB1 = FyR1[cB], yC1 = FyR1[cC];
    const bool mh = (m >= 1);
    const int hb = (b<<18) + (y<<9) + (m<<2);
    float4 pd = *(const float4*)(pred + hb);
    float4 td = *(const float4*)(tar + hb);
    const float* R = ref + (b<<18);
    const float wy1 = 1.f - wy;
    #pragma unroll
    for (int k = 0; k < 4; ++k){
      float wx;
      float lo0, hi0, lo1, hi1, flo0, fhi0, flo1, fhi1;
      if (k < 2){
        wx = mh ? (k == 0 ? 0.625f : 0.875f) : 0.f;
        lo0 = mh ? xA0 : xB0;  hi0 = mh ? xB0 : xC0;
        lo1 = mh ? xA1 : xB1;  hi1 = mh ? xB1 : xC1;
        flo0 = mh ? yA0 : yB0; fhi0 = mh ? yB0 : yC0;
        flo1 = mh ? yA1 : yB1; fhi1 = mh ? yB1 : yC1;
      } else {
        wx = (k == 2) ? 0.125f : 0.375f;
        lo0 = xB0;  hi0 = xC0;  lo1 = xB1;  hi1 = xC1;
        flo0 = yB0; fhi0 = yC0; flo1 = yB1; fhi1 = yC1;
      }
      const float w00 = wy1*(1.f-wx), w01 = wy1*wx, w10 = wy*(1.f-wx), w11 = wy*wx;
      const float fxv = 4.f*(w00*lo0 + w01*hi0 + w10*lo1 + w11*hi1);
      const float fyv = 4.f*(w00*flo0 + w01*fhi0 + w10*flo1 + w11*fhi1);
      const int x = (m<<2) + k;
      float ix = fminf(fmaxf((float)x - fxv, 0.f), (float)(HR-1));
      float iy = fminf(fmaxf((float)y - fyv, 0.f), (float)(HR-1));
      int gx0 = (int)ix; int gx1 = min(gx0+1, HR-1); float gwx = ix - (float)gx0;
      int gy0 = (int)iy; int gy1 = min(gy0+1, HR-1); float gwy = iy - (float)gy0;
      float v00 = R[(gy0<<9)+gx0], v01 = R[(gy0<<9)+gx1];
      float v10 = R[(gy1<<9)+gx0], v11 = R[(gy1<<9)+gx1];
      float tt = v00*(1.f-gwy)*(1.f-gwx) + v01*(1.f-gwy)*gwx
               + v10*gwy*(1.f-gwx)       + v11*gwy*gwx;
      float teacher = fmaxf(tt, 0.f);
      float pk = ((const float*)&pd)[k];
      float tk = ((const float*)&td)[k];
      float d  = pk - teacher;
      float ad = fabsf(d);
      float l  = ad < 0.2f ? 0.5f*d*d : 0.2f*(ad - 0.1f);
      float mm = (teacher > 0.05f || tk > 0.05f) ? 1.f : 0.f;
      acc += l*mm;
    }
  }
  acc *= (1.0f/(float)N_HR);
  #pragma unroll
  for (int o = 32; o > 0; o >>= 1) acc += __shfl_down(acc, o, 64);
  __shared__ float wsum[4];
  int lane = threadIdx.x & 63, wv = threadIdx.x >> 6;
  if (lane == 0) wsum[wv] = acc;
  __syncthreads();
  if (threadIdx.x == 0) atomicAdd(out, wsum[0]+wsum[1]+wsum[2]+wsum[3]);
}

extern "C" void kernel_launch(void* const* d_in, const int* in_sizes, int n_in,
                              void* d_out, int out_size, void* d_ws, size_t ws_size,
                              hipStream_t stream){
  const float* pred = (const float*)d_in[0];
  const float* tar  = (const float*)d_in[1];
  const float* ref  = (const float*)d_in[2];
  float* out = (float*)d_out;
  float* w = (float*)d_ws;
  float* prevW = w + 0*N_LR;
  float* currW = w + 1*N_LR;
  float* rain  = w + 2*N_LR;
  float* fxb   = w + 3*N_LR;
  float* fyb   = w + 4*N_LR;
  float* dsA   = w + 5*N_LR;   // wref_ds (dead after blur#1)
  float* dsB   = w + 6*N_LR;   // wtar_ds (dead after blur#1)
  // u64 argmin-key buffers: cKa overlays dsA+dsB (2*N_LR floats = N_LR u64),
  // cKb extends the workspace (peak 9*N_LR floats = 9 MB; r5-verified size).
  unsigned long long* cKa = (unsigned long long*)(w + 5*N_LR);
  unsigned long long* cKb = (unsigned long long*)(w + 7*N_LR);

  hipMemsetAsync(d_out, 0, sizeof(float), stream);

  const int tb = 256, nb = (N_LR + tb - 1)/tb;
  k_downsample<<<nb, tb, 0, stream>>>(ref, tar, dsA, dsB, rain);
  k_blur2<<<dim3(8, BATCH, 2), tb, 0, stream>>>(dsA, dsB, prevW, currW,
                                                nullptr, nullptr, nullptr, nullptr);
  k_cost_flow<<<dim3(LR/TH, BATCH, 2), 512, 0, stream>>>(prevW, currW, cKa, cKb);
  k_blur2<<<dim3(8, BATCH, 2), tb, 0, stream>>>(nullptr, nullptr, fxb, fyb,
                                                rain, rain, cKa, cKb);
  k_loss<<<2048, tb, 0, stream>>>(pred, tar, ref, fxb, fyb, out);
}